// Round 12
// baseline (344.850 us; speedup 1.0000x reference)
//
#include <hip/hip_runtime.h>
#include <hip/hip_bf16.h>

#define N_NODES 100000
#define N_EDGES 1600000
#define DIM 128
#define N_GRAPHS 512
#define N_CLASSES 10
#define SCAN_CHUNK 1024

// 2-pass radix CSR build
#define NBK 782                 // buckets of 128 dst nodes
#define EB 8192                 // edges per histogram/scatter block
#define NEB 196                 // ceil(N_EDGES / EB)
#define HN (NBK * NEB)          // 153272 hist entries (bucket-major)
#define NCH_HIST ((HN + SCAN_CHUNK - 1) / SCAN_CHUNK)       // 150
#define NCH_CNT ((N_NODES + SCAN_CHUNK - 1) / SCAN_CHUNK)   // 98

// node-parallel pool
#define POOL_CHUNK 128
#define NPB ((N_NODES + POOL_CHUNK - 1) / POOL_CHUNK)       // 782

typedef __attribute__((ext_vector_type(8))) short short8;
typedef __attribute__((ext_vector_type(4))) float floatx4;

__device__ __forceinline__ uint bfround(float f) {   // fp32 -> bf16 bits (RNE)
    uint u = __builtin_bit_cast(uint, f);
    return (u + 0x7fffu + ((u >> 16) & 1u)) >> 16;
}
__device__ __forceinline__ float bflo(uint u) { return __builtin_bit_cast(float, u << 16); }
__device__ __forceinline__ float bfhi(uint u) { return __builtin_bit_cast(float, u & 0xffff0000u); }

__device__ __forceinline__ void addrow(float* a, uint4 v) {
    a[0] += bflo(v.x); a[1] += bfhi(v.x);
    a[2] += bflo(v.y); a[3] += bfhi(v.y);
    a[4] += bflo(v.z); a[5] += bfhi(v.z);
    a[6] += bflo(v.w); a[7] += bfhi(v.w);
}

// ---------------- dtype conversion ----------------

__global__ void k_cvt_x(const float* __restrict__ x, ushort* __restrict__ xb, int n4) {
    int i = blockIdx.x * blockDim.x + threadIdx.x;
    int stride = gridDim.x * blockDim.x;
    for (; i < n4; i += stride) {
        floatx4 v = *(const floatx4*)(x + (size_t)i * 4);
        ushort4 o;
        o.x = (ushort)bfround(v.x);
        o.y = (ushort)bfround(v.y);
        o.z = (ushort)bfround(v.z);
        o.w = (ushort)bfround(v.w);
        *(ushort4*)(xb + (size_t)i * 4) = o;
    }
}

struct WPtrs { const float* w[6]; };

// W [K=128][N=128] fp32 -> Wt [N][K] bf16, 6 matrices in one launch (grid 6*64)
__global__ __launch_bounds__(256) void k_cvt_w(WPtrs wp, ushort* __restrict__ Wt) {
    int m = blockIdx.x >> 6;
    int idx = (blockIdx.x & 63) * 256 + threadIdx.x;   // 0..16383
    int n = idx >> 7, k = idx & 127;
    Wt[(size_t)m * 16384 + idx] = (ushort)bfround(wp.w[m][k * 128 + n]);
}

// ---------------- CSR build: 2-pass radix by bucket (dst>>7) ----------------
// All scatter writes are per-block contiguous; ZERO global atomics.

__global__ void k_zero(int* __restrict__ p, int n) {
    int i = blockIdx.x * blockDim.x + threadIdx.x;
    int stride = gridDim.x * blockDim.x;
    for (; i < n; i += stride) p[i] = 0;
}

// pass 1: per-edge-block LDS histogram over 782 buckets -> hist[b*NEB + blk]
__global__ __launch_bounds__(256) void k_hist(const int* __restrict__ dstv,
                                              int* __restrict__ hist) {
    __shared__ int cnt[NBK];
    int blk = blockIdx.x, tid = threadIdx.x;
    for (int i = tid; i < NBK; i += 256) cnt[i] = 0;
    __syncthreads();
    int base = blk * EB;
    int end = min(base + EB, N_EDGES);
    for (int i = base + tid; i < end; i += 256) atomicAdd(&cnt[dstv[i] >> 7], 1);
    __syncthreads();
    for (int b = tid; b < NBK; b += 256) hist[b * NEB + blk] = cnt[b];
}

// ---- generic hierarchical exclusive scan (n <= 256*1024) ----
__global__ __launch_bounds__(256) void k_reduce(const int* __restrict__ src, int n,
                                                int* __restrict__ chunk_sums) {
    int base = blockIdx.x * SCAN_CHUNK;
    int tid = threadIdx.x;
    int s = 0;
    for (int i = tid; i < SCAN_CHUNK; i += 256) {
        int idx = base + i;
        if (idx < n) s += src[idx];
    }
    __shared__ int red[256];
    red[tid] = s;
    __syncthreads();
    for (int off = 128; off > 0; off >>= 1) {
        if (tid < off) red[tid] += red[tid + off];
        __syncthreads();
    }
    if (tid == 0) chunk_sums[blockIdx.x] = red[0];
}

__global__ __launch_bounds__(256) void k_scan_c(int* __restrict__ chunk_sums, int nch,
                                                int* __restrict__ total_out) {
    __shared__ int sm[256];
    int tid = threadIdx.x;
    int v = (tid < nch) ? chunk_sums[tid] : 0;
    sm[tid] = v;
    __syncthreads();
    for (int off = 1; off < 256; off <<= 1) {
        int t = (tid >= off) ? sm[tid - off] : 0;
        __syncthreads();
        sm[tid] += t;
        __syncthreads();
    }
    if (tid < nch) chunk_sums[tid] = sm[tid] - v;   // exclusive
    if (tid == 255) *total_out = sm[255];
}

// exclusive scan apply; safe in-place (src==dst): each block touches only its chunk
__global__ __launch_bounds__(256) void k_apply(const int* __restrict__ src,
                                               const int* __restrict__ chunk_sums,
                                               int* __restrict__ dst, int n) {
    int base = blockIdx.x * SCAN_CHUNK;
    int tid = threadIdx.x;
    int i0 = base + tid * 4;
    int v[4];
    int s = 0;
    #pragma unroll
    for (int j = 0; j < 4; j++) {
        int idx = i0 + j;
        v[j] = (idx < n) ? src[idx] : 0;
        s += v[j];
    }
    __shared__ int sc[256];
    sc[tid] = s;
    __syncthreads();
    for (int off = 1; off < 256; off <<= 1) {
        int t = (tid >= off) ? sc[tid - off] : 0;
        __syncthreads();
        sc[tid] += t;
        __syncthreads();
    }
    int excl = sc[tid] - s + chunk_sums[blockIdx.x];
    #pragma unroll
    for (int j = 0; j < 4; j++) {
        int idx = i0 + j;
        if (idx < n) dst[idx] = excl;
        excl += v[j];
    }
}

// pass 2: scatter edges into bucket-sorted array. LDS cursor seeded with the
// global scanned base -> each (block,bucket) chunk is contiguous in memory,
// and adjacent blocks' chunks are adjacent. entry = src | (dst&127)<<17.
__global__ __launch_bounds__(256) void k_scatter(const int* __restrict__ srcv,
                                                 const int* __restrict__ dstv,
                                                 const int* __restrict__ hists,
                                                 uint* __restrict__ sorted) {
    __shared__ int cur[NBK];
    int blk = blockIdx.x, tid = threadIdx.x;
    for (int b = tid; b < NBK; b += 256) cur[b] = hists[b * NEB + blk];
    __syncthreads();
    int base = blk * EB;
    int end = min(base + EB, N_EDGES);
    for (int i = base + tid; i < end; i += 256) {
        int s = srcv[i], d = dstv[i];
        int p = atomicAdd(&cur[d >> 7], 1);
        sorted[p] = (uint)s | ((uint)(d & 127) << 17);
    }
}

// per-bucket node counts from sorted entries (contiguous read, LDS histogram)
__global__ __launch_bounds__(256) void k_bcount_s(const int* __restrict__ hists,
                                                  const uint* __restrict__ sorted,
                                                  int* __restrict__ counts) {
    __shared__ int cnt[128];
    int b = blockIdx.x, tid = threadIdx.x;
    if (tid < 128) cnt[tid] = 0;
    __syncthreads();
    int s0 = hists[b * NEB];
    int s1 = (b == NBK - 1) ? N_EDGES : hists[(b + 1) * NEB];
    for (int i = s0 + tid; i < s1; i += 256) atomicAdd(&cnt[(sorted[i] >> 17) & 127], 1);
    __syncthreads();
    int node = (b << 7) + tid;
    if (tid < 128 && node < N_NODES) counts[node] = cnt[tid];
}

// per-bucket fill of col: contiguous read; writes confined to this bucket's
// contiguous col region (~8KB) -> full-line writes
__global__ __launch_bounds__(256) void k_fill_s(const int* __restrict__ hists,
                                                const uint* __restrict__ sorted,
                                                const int* __restrict__ row_ptr,
                                                int* __restrict__ col) {
    __shared__ int cur[128];
    int b = blockIdx.x, tid = threadIdx.x;
    int node = (b << 7) + tid;
    if (tid < 128 && node < N_NODES) cur[tid] = row_ptr[node];
    __syncthreads();
    int s0 = hists[b * NEB];
    int s1 = (b == NBK - 1) ? N_EDGES : hists[(b + 1) * NEB];
    for (int i = s0 + tid; i < s1; i += 256) {
        uint e = sorted[i];
        int p = atomicAdd(&cur[(e >> 17) & 127], 1);
        col[p] = (int)(e & 0x1FFFFu);
    }
}

// ---------------- GIN aggregation: 2 nodes per wave, 8 loads in flight ------
// AT ROOFLINE (R8 vs R11 A/B: 4-deep and 8-deep both 60us, fetch 187MB @ 3.6TB/s
// -> random-256B-gather fabric bound). Uniform trips, clamped shfl (R3 lesson).
__global__ __launch_bounds__(256) void k_agg(const uint4* __restrict__ xr,
                                             const int* __restrict__ row_ptr,
                                             const int* __restrict__ col,
                                             uint4* __restrict__ hr) {
    int wv = threadIdx.x >> 6;
    int nA = blockIdx.x * 8 + wv * 2;      // wave-uniform
    if (nA >= N_NODES) return;
    int nB = nA + 1;
    bool hasB = nB < N_NODES;
    int lane = threadIdx.x & 63;
    int grp = lane >> 4;
    int l16 = lane & 15;

    float accA[8], accB[8];
    #pragma unroll
    for (int i = 0; i < 8; i++) { accA[i] = 0.f; accB[i] = 0.f; }
    if (grp == 0) {
        uint4 sv = xr[(size_t)nA * 16 + l16];      // self term A (eps=0)
        accA[0] = bflo(sv.x); accA[1] = bfhi(sv.x);
        accA[2] = bflo(sv.y); accA[3] = bfhi(sv.y);
        accA[4] = bflo(sv.z); accA[5] = bfhi(sv.z);
        accA[6] = bflo(sv.w); accA[7] = bfhi(sv.w);
    } else if (grp == 1 && hasB) {
        uint4 sv = xr[(size_t)nB * 16 + l16];      // self term B
        accB[0] = bflo(sv.x); accB[1] = bfhi(sv.x);
        accB[2] = bflo(sv.y); accB[3] = bfhi(sv.y);
        accB[4] = bflo(sv.z); accB[5] = bfhi(sv.z);
        accB[6] = bflo(sv.w); accB[7] = bfhi(sv.w);
    }

    int jA = row_ptr[nA], eA = row_ptr[nA + 1];
    int jB = hasB ? row_ptr[nB] : 0;
    int eB = hasB ? row_ptr[nB + 1] : 0;

    while (jA < eA || jB < eB) {
        int chunkA = eA - jA; chunkA = chunkA < 0 ? 0 : (chunkA > 64 ? 64 : chunkA);
        int chunkB = eB - jB; chunkB = chunkB < 0 ? 0 : (chunkB > 64 ? 64 : chunkB);
        int myA = (lane < chunkA) ? col[jA + lane] : 0;
        int myB = (lane < chunkB) ? col[jB + lane] : 0;
        int cm = chunkA > chunkB ? chunkA : chunkB;
        int iters = (cm + 15) >> 4;             // wave-uniform
        for (int f = 0; f < iters; f++) {
            int p = (f << 4) + grp;
            int a0 = __shfl(myA, (p      < chunkA) ? p      : 0);
            int a1 = __shfl(myA, (p + 4  < chunkA) ? p + 4  : 0);
            int a2 = __shfl(myA, (p + 8  < chunkA) ? p + 8  : 0);
            int a3 = __shfl(myA, (p + 12 < chunkA) ? p + 12 : 0);
            int b0 = __shfl(myB, (p      < chunkB) ? p      : 0);
            int b1 = __shfl(myB, (p + 4  < chunkB) ? p + 4  : 0);
            int b2 = __shfl(myB, (p + 8  < chunkB) ? p + 8  : 0);
            int b3 = __shfl(myB, (p + 12 < chunkB) ? p + 12 : 0);
            uint4 vA0 = xr[(size_t)a0 * 16 + l16];   // 8 loads in flight
            uint4 vA1 = xr[(size_t)a1 * 16 + l16];
            uint4 vA2 = xr[(size_t)a2 * 16 + l16];
            uint4 vA3 = xr[(size_t)a3 * 16 + l16];
            uint4 vB0 = xr[(size_t)b0 * 16 + l16];
            uint4 vB1 = xr[(size_t)b1 * 16 + l16];
            uint4 vB2 = xr[(size_t)b2 * 16 + l16];
            uint4 vB3 = xr[(size_t)b3 * 16 + l16];
            if (p < chunkA)      addrow(accA, vA0);
            if (p + 4 < chunkA)  addrow(accA, vA1);
            if (p + 8 < chunkA)  addrow(accA, vA2);
            if (p + 12 < chunkA) addrow(accA, vA3);
            if (p < chunkB)      addrow(accB, vB0);
            if (p + 4 < chunkB)  addrow(accB, vB1);
            if (p + 8 < chunkB)  addrow(accB, vB2);
            if (p + 12 < chunkB) addrow(accB, vB3);
        }
        jA += 64; jB += 64;
    }

    #pragma unroll
    for (int i = 0; i < 8; i++) {
        accA[i] += __shfl_xor(accA[i], 16);
        accA[i] += __shfl_xor(accA[i], 32);
        accB[i] += __shfl_xor(accB[i], 16);
        accB[i] += __shfl_xor(accB[i], 32);
    }

    if (grp == 0) {
        uint4 o;
        o.x = bfround(accA[0]) | (bfround(accA[1]) << 16);
        o.y = bfround(accA[2]) | (bfround(accA[3]) << 16);
        o.z = bfround(accA[4]) | (bfround(accA[5]) << 16);
        o.w = bfround(accA[6]) | (bfround(accA[7]) << 16);
        hr[(size_t)nA * 16 + l16] = o;
    } else if (grp == 1 && hasB) {
        uint4 o;
        o.x = bfround(accB[0]) | (bfround(accB[1]) << 16);
        o.y = bfround(accB[2]) | (bfround(accB[3]) << 16);
        o.z = bfround(accB[4]) | (bfround(accB[5]) << 16);
        o.w = bfround(accB[6]) | (bfround(accB[7]) << 16);
        hr[(size_t)nB * 16 + l16] = o;
    }
}

// ---------------- fused MFMA MLP (staged, SINGLE 16KB LDS buffer) -----------
// One buffer reused h -> t -> out with drain barriers between phases.
// 16KB LDS -> 8 blocks/CU (2048 threads, 100% occupancy) vs 5 at 32KB.
__device__ __forceinline__ int loff(int row, int byte) {
    return row * 256 + (byte ^ ((row & 7) << 4));
}

__global__ __launch_bounds__(256) void k_mlp(const ushort* __restrict__ hin,
                                             ushort* __restrict__ xout,
                                             const ushort* __restrict__ W1t,
                                             const float* __restrict__ b1,
                                             const ushort* __restrict__ W2t,
                                             const float* __restrict__ b2) {
    __shared__ alignas(16) char hT[64 * 256];   // h, then t, then out
    int tid = threadIdx.x;
    int lane = tid & 63;
    int wave = tid >> 6;
    int node0 = blockIdx.x * 64;
    int l15 = lane & 15;
    int lhi = lane >> 4;
    int ncol0 = wave * 32;

    // ---- stage h tile (coalesced 16B, swizzled) ----
    #pragma unroll
    for (int it = 0; it < 4; ++it) {
        int idx = it * 256 + tid;
        int row = idx >> 4;
        int cb = (idx & 15) * 16;
        int gn = node0 + row;
        floatx4 v = {0.f, 0.f, 0.f, 0.f};
        if (gn < N_NODES) v = *(const floatx4*)(hin + (size_t)gn * 128 + cb / 2);
        *(floatx4*)(hT + loff(row, cb)) = v;
    }
    __syncthreads();

    // ---- B1 fragments + phase A ----
    short8 bf[4][2];
    #pragma unroll
    for (int ks = 0; ks < 4; ks++)
        #pragma unroll
        for (int nf = 0; nf < 2; nf++) {
            int nrow = ncol0 + nf * 16 + l15;
            bf[ks][nf] = *(const short8*)(W1t + nrow * 128 + ks * 32 + lhi * 8);
        }

    floatx4 acc[4][2];
    #pragma unroll
    for (int m = 0; m < 4; m++)
        #pragma unroll
        for (int nf = 0; nf < 2; nf++) {
            float bias = b1[ncol0 + nf * 16 + l15];
            acc[m][nf] = (floatx4){bias, bias, bias, bias};
        }

    #pragma unroll
    for (int ks = 0; ks < 4; ks++) {
        short8 af[4];
        #pragma unroll
        for (int m = 0; m < 4; m++)
            af[m] = *(const short8*)(hT + loff(m * 16 + l15, ks * 64 + lhi * 16));
        #pragma unroll
        for (int m = 0; m < 4; m++)
            #pragma unroll
            for (int nf = 0; nf < 2; nf++)
                acc[m][nf] = __builtin_amdgcn_mfma_f32_16x16x32_bf16(af[m], bf[ks][nf], acc[m][nf], 0, 0, 0);
    }
    __syncthreads();   // drain all phase-A hT reads before overwrite

    // ---- write t = relu(acc) into hT ----
    #pragma unroll
    for (int m = 0; m < 4; m++)
        #pragma unroll
        for (int nf = 0; nf < 2; nf++) {
            int colb = (ncol0 + nf * 16 + l15) * 2;
            #pragma unroll
            for (int j = 0; j < 4; j++) {
                int row = m * 16 + lhi * 4 + j;
                float t = acc[m][nf][j];
                t = t > 0.f ? t : 0.f;
                *(ushort*)(hT + loff(row, colb)) = (ushort)bfround(t);
            }
        }
    __syncthreads();

    // ---- B2 fragments + phase B ----
    #pragma unroll
    for (int ks = 0; ks < 4; ks++)
        #pragma unroll
        for (int nf = 0; nf < 2; nf++) {
            int nrow = ncol0 + nf * 16 + l15;
            bf[ks][nf] = *(const short8*)(W2t + nrow * 128 + ks * 32 + lhi * 8);
        }
    #pragma unroll
    for (int m = 0; m < 4; m++)
        #pragma unroll
        for (int nf = 0; nf < 2; nf++) {
            float bias = b2[ncol0 + nf * 16 + l15];
            acc[m][nf] = (floatx4){bias, bias, bias, bias};
        }

    #pragma unroll
    for (int ks = 0; ks < 4; ks++) {
        short8 af[4];
        #pragma unroll
        for (int m = 0; m < 4; m++)
            af[m] = *(const short8*)(hT + loff(m * 16 + l15, ks * 64 + lhi * 16));
        #pragma unroll
        for (int m = 0; m < 4; m++)
            #pragma unroll
            for (int nf = 0; nf < 2; nf++)
                acc[m][nf] = __builtin_amdgcn_mfma_f32_16x16x32_bf16(af[m], bf[ks][nf], acc[m][nf], 0, 0, 0);
    }
    __syncthreads();   // drain phase-B reads before overwrite

    // ---- write out = relu(acc) into hT, then coalesced store ----
    #pragma unroll
    for (int m = 0; m < 4; m++)
        #pragma unroll
        for (int nf = 0; nf < 2; nf++) {
            int colb = (ncol0 + nf * 16 + l15) * 2;
            #pragma unroll
            for (int j = 0; j < 4; j++) {
                int row = m * 16 + lhi * 4 + j;
                float t = acc[m][nf][j];
                t = t > 0.f ? t : 0.f;
                *(ushort*)(hT + loff(row, colb)) = (ushort)bfround(t);
            }
        }
    __syncthreads();
    #pragma unroll
    for (int it = 0; it < 4; ++it) {
        int idx = it * 256 + tid;
        int row = idx >> 4;
        int cb = (idx & 15) * 16;
        int gn = node0 + row;
        if (gn < N_NODES)
            *(floatx4*)(xout + (size_t)gn * 128 + cb / 2) = *(const floatx4*)(hT + loff(row, cb));
    }
}

// ---------------- global add pool (node-parallel, batch sorted) ----------------
__global__ __launch_bounds__(256) void k_pool(const uint* __restrict__ x,
                                              const int* __restrict__ batch,
                                              float* __restrict__ pooled) {
    int n0 = blockIdx.x * POOL_CHUNK;
    int wave = threadIdx.x >> 6;
    int lane = threadIdx.x & 63;
    float a0 = 0.f, a1 = 0.f;
    int cur = -1;
    int endn = min(n0 + POOL_CHUNK, N_NODES);
    for (int n = n0 + wave; n < endn; n += 4) {
        int g = batch[n];                      // wave-uniform
        if (g != cur) {
            if (cur >= 0) {
                atomicAdd(&pooled[cur * 128 + lane * 2], a0);
                atomicAdd(&pooled[cur * 128 + lane * 2 + 1], a1);
            }
            cur = g; a0 = 0.f; a1 = 0.f;
        }
        uint v = x[(size_t)n * 64 + lane];     // 256B/row coalesced
        a0 += bflo(v); a1 += bfhi(v);
    }
    if (cur >= 0) {
        atomicAdd(&pooled[cur * 128 + lane * 2], a0);
        atomicAdd(&pooled[cur * 128 + lane * 2 + 1], a1);
    }
}

__global__ __launch_bounds__(64) void k_final(const float* __restrict__ pooled,
                                              const float* __restrict__ wl,
                                              const float* __restrict__ bl,
                                              float* __restrict__ out) {
    int g = blockIdx.x;
    int o = threadIdx.x;
    if (o >= N_CLASSES) return;
    float acc = bl[o];
    for (int k = 0; k < 128; k++) acc += pooled[g * 128 + k] * wl[k * N_CLASSES + o];
    out[g * N_CLASSES + o] = acc;
}

// ---------------- launch ----------------

extern "C" void kernel_launch(void* const* d_in, const int* in_sizes, int n_in,
                              void* d_out, int out_size, void* d_ws, size_t ws_size,
                              hipStream_t stream) {
    const float* x0  = (const float*)d_in[0];
    const int* ei    = (const int*)d_in[1];
    const int* batch = (const int*)d_in[2];
    const float* W1[3] = {(const float*)d_in[3], (const float*)d_in[7],  (const float*)d_in[11]};
    const float* B1[3] = {(const float*)d_in[4], (const float*)d_in[8],  (const float*)d_in[12]};
    const float* W2[3] = {(const float*)d_in[5], (const float*)d_in[9],  (const float*)d_in[13]};
    const float* B2[3] = {(const float*)d_in[6], (const float*)d_in[10], (const float*)d_in[14]};
    const float* wl = (const float*)d_in[15];
    const float* bl = (const float*)d_in[16];
    float* out = (float*)d_out;

    const int* srcv = ei;
    const int* dstv = ei + N_EDGES;

    // workspace layout
    char* w = (char*)d_ws;
    ushort* xb = (ushort*)w;                                   // N*128 bf16 (25.6MB)
    ushort* hb = xb + (size_t)N_NODES * DIM;                   // N*128 bf16 (25.6MB)
    ushort* wt = hb + (size_t)N_NODES * DIM;                   // 6*128*128 bf16
    float* pooled = (float*)(wt + 6 * 128 * 128);              // 512*128 f32
    int* row_ptr = (int*)(pooled + N_GRAPHS * DIM);            // N+2
    int* counts  = row_ptr + (N_NODES + 2);                    // N
    int* colidx  = counts + N_NODES;                           // E (6.4MB)
    int* chunk_sums = colidx + N_EDGES;                        // 256
    int* hist    = chunk_sums + 256;                           // HN+1 (613KB)
    uint* sorted = (uint*)(hist + HN + 1);                     // E (6.4MB)

    // ---- dtype conversion + pooled zero-init ----
    hipLaunchKernelGGL(k_cvt_x, dim3(2048), dim3(256), 0, stream, x0, xb, N_NODES * DIM / 4);
    WPtrs wp;
    wp.w[0] = W1[0]; wp.w[1] = W2[0]; wp.w[2] = W1[1];
    wp.w[3] = W2[1]; wp.w[4] = W1[2]; wp.w[5] = W2[2];
    hipLaunchKernelGGL(k_cvt_w, dim3(6 * 64), dim3(256), 0, stream, wp, wt);
    hipLaunchKernelGGL(k_zero, dim3(64), dim3(256), 0, stream, (int*)pooled, N_GRAPHS * DIM);

    // ---- CSR build: 2-pass radix ----
    hipLaunchKernelGGL(k_hist, dim3(NEB), dim3(256), 0, stream, dstv, hist);
    hipLaunchKernelGGL(k_reduce, dim3(NCH_HIST), dim3(256), 0, stream, hist, HN, chunk_sums);
    hipLaunchKernelGGL(k_scan_c, dim3(1), dim3(256), 0, stream, chunk_sums, NCH_HIST, hist + HN);
    hipLaunchKernelGGL(k_apply, dim3(NCH_HIST), dim3(256), 0, stream, hist, chunk_sums, hist, HN);
    hipLaunchKernelGGL(k_scatter, dim3(NEB), dim3(256), 0, stream, srcv, dstv, hist, sorted);
    hipLaunchKernelGGL(k_bcount_s, dim3(NBK), dim3(256), 0, stream, hist, sorted, counts);
    hipLaunchKernelGGL(k_reduce, dim3(NCH_CNT), dim3(256), 0, stream, counts, N_NODES, chunk_sums);
    hipLaunchKernelGGL(k_scan_c, dim3(1), dim3(256), 0, stream, chunk_sums, NCH_CNT, row_ptr + N_NODES);
    hipLaunchKernelGGL(k_apply, dim3(NCH_CNT), dim3(256), 0, stream, counts, chunk_sums, row_ptr, N_NODES);
    hipLaunchKernelGGL(k_fill_s, dim3(NBK), dim3(256), 0, stream, hist, sorted, row_ptr, colidx);

    // ---- 3 GIN layers: agg (xb -> hb), mlp (hb -> xb) ----
    dim3 aggGrid((N_NODES + 7) / 8), aggBlk(256);   // 2 nodes/wave, 8/block
    dim3 mlpGrid((N_NODES + 63) / 64), mlpBlk(256);
    for (int l = 0; l < 3; l++) {
        hipLaunchKernelGGL(k_agg, aggGrid, aggBlk, 0, stream,
                           (const uint4*)xb, row_ptr, colidx, (uint4*)hb);
        hipLaunchKernelGGL(k_mlp, mlpGrid, mlpBlk, 0, stream,
                           hb, xb, wt + (size_t)(2 * l) * 16384, B1[l],
                           wt + (size_t)(2 * l + 1) * 16384, B2[l]);
    }

    // ---- pool + final ----
    hipLaunchKernelGGL(k_pool, dim3(NPB), dim3(256), 0, stream, (const uint*)xb, batch, pooled);
    hipLaunchKernelGGL(k_final, dim3(N_GRAPHS), dim3(64), 0, stream, pooled, wl, bl, out);
}

// Round 13
// 330.645 us; speedup vs baseline: 1.0430x; 1.0430x over previous
//
#include <hip/hip_runtime.h>
#include <hip/hip_bf16.h>

#define N_NODES 100000
#define N_EDGES 1600000
#define DIM 128
#define N_GRAPHS 512
#define N_CLASSES 10
#define SCAN_CHUNK 1024

// 2-pass radix CSR build
#define NBK 782                 // buckets of 128 dst nodes
#define EB 8192                 // edges per histogram/scatter block
#define NEB 196                 // ceil(N_EDGES / EB)
#define HN (NBK * NEB)          // 153272 hist entries (bucket-major)
#define NCH_HIST ((HN + SCAN_CHUNK - 1) / SCAN_CHUNK)       // 150

// node-parallel pool
#define POOL_CHUNK 128
#define NPB ((N_NODES + POOL_CHUNK - 1) / POOL_CHUNK)       // 782

typedef __attribute__((ext_vector_type(8))) short short8;
typedef __attribute__((ext_vector_type(4))) float floatx4;

__device__ __forceinline__ uint bfround(float f) {   // fp32 -> bf16 bits (RNE)
    uint u = __builtin_bit_cast(uint, f);
    return (u + 0x7fffu + ((u >> 16) & 1u)) >> 16;
}
__device__ __forceinline__ float bflo(uint u) { return __builtin_bit_cast(float, u << 16); }
__device__ __forceinline__ float bfhi(uint u) { return __builtin_bit_cast(float, u & 0xffff0000u); }

__device__ __forceinline__ void addrow(float* a, uint4 v) {
    a[0] += bflo(v.x); a[1] += bfhi(v.x);
    a[2] += bflo(v.y); a[3] += bfhi(v.y);
    a[4] += bflo(v.z); a[5] += bfhi(v.z);
    a[6] += bflo(v.w); a[7] += bfhi(v.w);
}

struct WPtrs { const float* w[6]; };

// ---------------- dtype conversion: x AND the 6 weight matrices ----------------
__global__ void k_cvt_x(const float* __restrict__ x, ushort* __restrict__ xb,
                        WPtrs wp, ushort* __restrict__ wt) {
    int stride = gridDim.x * blockDim.x;
    int t0 = blockIdx.x * blockDim.x + threadIdx.x;
    for (int i = t0; i < N_NODES * DIM / 4; i += stride) {
        floatx4 v = *(const floatx4*)(x + (size_t)i * 4);
        ushort4 o;
        o.x = (ushort)bfround(v.x);
        o.y = (ushort)bfround(v.y);
        o.z = (ushort)bfround(v.z);
        o.w = (ushort)bfround(v.w);
        *(ushort4*)(xb + (size_t)i * 4) = o;
    }
    // W [K=128][N=128] fp32 -> Wt [N][K] bf16, 6 matrices
    for (int j = t0; j < 6 * 16384; j += stride) {
        int m = j >> 14, idx = j & 16383;
        int n = idx >> 7, k = idx & 127;
        wt[j] = (ushort)bfround(wp.w[m][k * 128 + n]);
    }
}

// ---------------- CSR build: 2-pass radix by bucket (dst>>7) ----------------
// All scatter writes are per-block contiguous; ZERO global atomics.

// pass 1: per-edge-block LDS histogram over 782 buckets -> hist[b*NEB + blk]
// (also zero-inits pooled, saving a launch; k_pool runs much later)
__global__ __launch_bounds__(256) void k_hist(const int* __restrict__ dstv,
                                              int* __restrict__ hist,
                                              float* __restrict__ pooled) {
    int gt = blockIdx.x * 256 + threadIdx.x;
    for (int i = gt; i < N_GRAPHS * DIM; i += NEB * 256) pooled[i] = 0.f;

    __shared__ int cnt[NBK];
    int blk = blockIdx.x, tid = threadIdx.x;
    for (int i = tid; i < NBK; i += 256) cnt[i] = 0;
    __syncthreads();
    int base = blk * EB;
    int end = min(base + EB, N_EDGES);
    for (int i = base + tid; i < end; i += 256) atomicAdd(&cnt[dstv[i] >> 7], 1);
    __syncthreads();
    for (int b = tid; b < NBK; b += 256) hist[b * NEB + blk] = cnt[b];
}

// ---- hierarchical exclusive scan over hist (HN entries) ----
__global__ __launch_bounds__(256) void k_reduce(const int* __restrict__ src, int n,
                                                int* __restrict__ chunk_sums) {
    int base = blockIdx.x * SCAN_CHUNK;
    int tid = threadIdx.x;
    int s = 0;
    for (int i = tid; i < SCAN_CHUNK; i += 256) {
        int idx = base + i;
        if (idx < n) s += src[idx];
    }
    __shared__ int red[256];
    red[tid] = s;
    __syncthreads();
    for (int off = 128; off > 0; off >>= 1) {
        if (tid < off) red[tid] += red[tid + off];
        __syncthreads();
    }
    if (tid == 0) chunk_sums[blockIdx.x] = red[0];
}

__global__ __launch_bounds__(256) void k_scan_c(int* __restrict__ chunk_sums, int nch) {
    __shared__ int sm[256];
    int tid = threadIdx.x;
    int v = (tid < nch) ? chunk_sums[tid] : 0;
    sm[tid] = v;
    __syncthreads();
    for (int off = 1; off < 256; off <<= 1) {
        int t = (tid >= off) ? sm[tid - off] : 0;
        __syncthreads();
        sm[tid] += t;
        __syncthreads();
    }
    if (tid < nch) chunk_sums[tid] = sm[tid] - v;   // exclusive
}

// exclusive scan apply; safe in-place (src==dst)
__global__ __launch_bounds__(256) void k_apply(const int* __restrict__ src,
                                               const int* __restrict__ chunk_sums,
                                               int* __restrict__ dst, int n) {
    int base = blockIdx.x * SCAN_CHUNK;
    int tid = threadIdx.x;
    int i0 = base + tid * 4;
    int v[4];
    int s = 0;
    #pragma unroll
    for (int j = 0; j < 4; j++) {
        int idx = i0 + j;
        v[j] = (idx < n) ? src[idx] : 0;
        s += v[j];
    }
    __shared__ int sc[256];
    sc[tid] = s;
    __syncthreads();
    for (int off = 1; off < 256; off <<= 1) {
        int t = (tid >= off) ? sc[tid - off] : 0;
        __syncthreads();
        sc[tid] += t;
        __syncthreads();
    }
    int excl = sc[tid] - s + chunk_sums[blockIdx.x];
    #pragma unroll
    for (int j = 0; j < 4; j++) {
        int idx = i0 + j;
        if (idx < n) dst[idx] = excl;
        excl += v[j];
    }
}

// pass 2: scatter edges into bucket-sorted array. LDS cursor seeded with the
// global scanned base -> each (block,bucket) chunk is contiguous in memory.
// entry = src | (dst&127)<<17.
__global__ __launch_bounds__(256) void k_scatter(const int* __restrict__ srcv,
                                                 const int* __restrict__ dstv,
                                                 const int* __restrict__ hists,
                                                 uint* __restrict__ sorted) {
    __shared__ int cur[NBK];
    int blk = blockIdx.x, tid = threadIdx.x;
    for (int b = tid; b < NBK; b += 256) cur[b] = hists[b * NEB + blk];
    __syncthreads();
    int base = blk * EB;
    int end = min(base + EB, N_EDGES);
    for (int i = base + tid; i < end; i += 256) {
        int s = srcv[i], d = dstv[i];
        int p = atomicAdd(&cur[d >> 7], 1);
        sorted[p] = (uint)s | ((uint)(d & 127) << 17);
    }
}

// merged bcount + per-node scan + fill: per bucket, LDS histogram of the 128
// node counts -> LDS exclusive scan -> row_ptr[node] = bucket_base + excl
// (bucket_base = hists[b*NEB], already globally scanned) -> fill col via LDS
// cursors. Replaces 5 kernels (bcount, reduce, scan, apply, fill) and a full
// re-read of sorted+counts.
__global__ __launch_bounds__(256) void k_build(const int* __restrict__ hists,
                                               const uint* __restrict__ sorted,
                                               int* __restrict__ row_ptr,
                                               int* __restrict__ col) {
    __shared__ int cnt[128];
    __shared__ int scn[128];
    __shared__ int cur[128];
    int b = blockIdx.x, tid = threadIdx.x;
    if (tid < 128) cnt[tid] = 0;
    __syncthreads();
    int s0 = hists[b * NEB];
    int s1 = (b == NBK - 1) ? N_EDGES : hists[(b + 1) * NEB];
    for (int i = s0 + tid; i < s1; i += 256) atomicAdd(&cnt[(sorted[i] >> 17) & 127], 1);
    __syncthreads();
    // Hillis-Steele inclusive scan over 128 counts (threads 0..127)
    if (tid < 128) scn[tid] = cnt[tid];
    __syncthreads();
    for (int off = 1; off < 128; off <<= 1) {
        int t = (tid < 128 && tid >= off) ? scn[tid - off] : 0;
        __syncthreads();
        if (tid < 128) scn[tid] += t;
        __syncthreads();
    }
    int node = (b << 7) + tid;
    if (tid < 128) {
        int excl = s0 + scn[tid] - cnt[tid];
        cur[tid] = excl;
        if (node < N_NODES) row_ptr[node] = excl;
    }
    if (b == 0 && tid == 0) row_ptr[N_NODES] = N_EDGES;
    __syncthreads();
    for (int i = s0 + tid; i < s1; i += 256) {
        uint e = sorted[i];
        int p = atomicAdd(&cur[(e >> 17) & 127], 1);
        col[p] = (int)(e & 0x1FFFFu);
    }
}

// ---------------- GIN aggregation: 2 nodes per wave, 8 loads in flight ------
// AT ROOFLINE (R8 vs R11 A/B: 4-deep and 8-deep both 60us, fetch 187MB @ 3.6TB/s
// -> random-256B-gather fabric bound). Uniform trips, clamped shfl (R3 lesson).
__global__ __launch_bounds__(256) void k_agg(const uint4* __restrict__ xr,
                                             const int* __restrict__ row_ptr,
                                             const int* __restrict__ col,
                                             uint4* __restrict__ hr) {
    int wv = threadIdx.x >> 6;
    int nA = blockIdx.x * 8 + wv * 2;      // wave-uniform
    if (nA >= N_NODES) return;
    int nB = nA + 1;
    bool hasB = nB < N_NODES;
    int lane = threadIdx.x & 63;
    int grp = lane >> 4;
    int l16 = lane & 15;

    float accA[8], accB[8];
    #pragma unroll
    for (int i = 0; i < 8; i++) { accA[i] = 0.f; accB[i] = 0.f; }
    if (grp == 0) {
        uint4 sv = xr[(size_t)nA * 16 + l16];      // self term A (eps=0)
        accA[0] = bflo(sv.x); accA[1] = bfhi(sv.x);
        accA[2] = bflo(sv.y); accA[3] = bfhi(sv.y);
        accA[4] = bflo(sv.z); accA[5] = bfhi(sv.z);
        accA[6] = bflo(sv.w); accA[7] = bfhi(sv.w);
    } else if (grp == 1 && hasB) {
        uint4 sv = xr[(size_t)nB * 16 + l16];      // self term B
        accB[0] = bflo(sv.x); accB[1] = bfhi(sv.x);
        accB[2] = bflo(sv.y); accB[3] = bfhi(sv.y);
        accB[4] = bflo(sv.z); accB[5] = bfhi(sv.z);
        accB[6] = bflo(sv.w); accB[7] = bfhi(sv.w);
    }

    int jA = row_ptr[nA], eA = row_ptr[nA + 1];
    int jB = hasB ? row_ptr[nB] : 0;
    int eB = hasB ? row_ptr[nB + 1] : 0;

    while (jA < eA || jB < eB) {
        int chunkA = eA - jA; chunkA = chunkA < 0 ? 0 : (chunkA > 64 ? 64 : chunkA);
        int chunkB = eB - jB; chunkB = chunkB < 0 ? 0 : (chunkB > 64 ? 64 : chunkB);
        int myA = (lane < chunkA) ? col[jA + lane] : 0;
        int myB = (lane < chunkB) ? col[jB + lane] : 0;
        int cm = chunkA > chunkB ? chunkA : chunkB;
        int iters = (cm + 15) >> 4;             // wave-uniform
        for (int f = 0; f < iters; f++) {
            int p = (f << 4) + grp;
            int a0 = __shfl(myA, (p      < chunkA) ? p      : 0);
            int a1 = __shfl(myA, (p + 4  < chunkA) ? p + 4  : 0);
            int a2 = __shfl(myA, (p + 8  < chunkA) ? p + 8  : 0);
            int a3 = __shfl(myA, (p + 12 < chunkA) ? p + 12 : 0);
            int b0 = __shfl(myB, (p      < chunkB) ? p      : 0);
            int b1 = __shfl(myB, (p + 4  < chunkB) ? p + 4  : 0);
            int b2 = __shfl(myB, (p + 8  < chunkB) ? p + 8  : 0);
            int b3 = __shfl(myB, (p + 12 < chunkB) ? p + 12 : 0);
            uint4 vA0 = xr[(size_t)a0 * 16 + l16];   // 8 loads in flight
            uint4 vA1 = xr[(size_t)a1 * 16 + l16];
            uint4 vA2 = xr[(size_t)a2 * 16 + l16];
            uint4 vA3 = xr[(size_t)a3 * 16 + l16];
            uint4 vB0 = xr[(size_t)b0 * 16 + l16];
            uint4 vB1 = xr[(size_t)b1 * 16 + l16];
            uint4 vB2 = xr[(size_t)b2 * 16 + l16];
            uint4 vB3 = xr[(size_t)b3 * 16 + l16];
            if (p < chunkA)      addrow(accA, vA0);
            if (p + 4 < chunkA)  addrow(accA, vA1);
            if (p + 8 < chunkA)  addrow(accA, vA2);
            if (p + 12 < chunkA) addrow(accA, vA3);
            if (p < chunkB)      addrow(accB, vB0);
            if (p + 4 < chunkB)  addrow(accB, vB1);
            if (p + 8 < chunkB)  addrow(accB, vB2);
            if (p + 12 < chunkB) addrow(accB, vB3);
        }
        jA += 64; jB += 64;
    }

    #pragma unroll
    for (int i = 0; i < 8; i++) {
        accA[i] += __shfl_xor(accA[i], 16);
        accA[i] += __shfl_xor(accA[i], 32);
        accB[i] += __shfl_xor(accB[i], 16);
        accB[i] += __shfl_xor(accB[i], 32);
    }

    if (grp == 0) {
        uint4 o;
        o.x = bfround(accA[0]) | (bfround(accA[1]) << 16);
        o.y = bfround(accA[2]) | (bfround(accA[3]) << 16);
        o.z = bfround(accA[4]) | (bfround(accA[5]) << 16);
        o.w = bfround(accA[6]) | (bfround(accA[7]) << 16);
        hr[(size_t)nA * 16 + l16] = o;
    } else if (grp == 1 && hasB) {
        uint4 o;
        o.x = bfround(accB[0]) | (bfround(accB[1]) << 16);
        o.y = bfround(accB[2]) | (bfround(accB[3]) << 16);
        o.z = bfround(accB[4]) | (bfround(accB[5]) << 16);
        o.w = bfround(accB[6]) | (bfround(accB[7]) << 16);
        hr[(size_t)nB * 16 + l16] = o;
    }
}

// ---------------- fused MFMA MLP (staged, single 16KB LDS buffer) -----------
__device__ __forceinline__ int loff(int row, int byte) {
    return row * 256 + (byte ^ ((row & 7) << 4));
}

__global__ __launch_bounds__(256) void k_mlp(const ushort* __restrict__ hin,
                                             ushort* __restrict__ xout,
                                             const ushort* __restrict__ W1t,
                                             const float* __restrict__ b1,
                                             const ushort* __restrict__ W2t,
                                             const float* __restrict__ b2) {
    __shared__ alignas(16) char hT[64 * 256];   // h, then t, then out
    int tid = threadIdx.x;
    int lane = tid & 63;
    int wave = tid >> 6;
    int node0 = blockIdx.x * 64;
    int l15 = lane & 15;
    int lhi = lane >> 4;
    int ncol0 = wave * 32;

    #pragma unroll
    for (int it = 0; it < 4; ++it) {
        int idx = it * 256 + tid;
        int row = idx >> 4;
        int cb = (idx & 15) * 16;
        int gn = node0 + row;
        floatx4 v = {0.f, 0.f, 0.f, 0.f};
        if (gn < N_NODES) v = *(const floatx4*)(hin + (size_t)gn * 128 + cb / 2);
        *(floatx4*)(hT + loff(row, cb)) = v;
    }
    __syncthreads();

    short8 bf[4][2];
    #pragma unroll
    for (int ks = 0; ks < 4; ks++)
        #pragma unroll
        for (int nf = 0; nf < 2; nf++) {
            int nrow = ncol0 + nf * 16 + l15;
            bf[ks][nf] = *(const short8*)(W1t + nrow * 128 + ks * 32 + lhi * 8);
        }

    floatx4 acc[4][2];
    #pragma unroll
    for (int m = 0; m < 4; m++)
        #pragma unroll
        for (int nf = 0; nf < 2; nf++) {
            float bias = b1[ncol0 + nf * 16 + l15];
            acc[m][nf] = (floatx4){bias, bias, bias, bias};
        }

    #pragma unroll
    for (int ks = 0; ks < 4; ks++) {
        short8 af[4];
        #pragma unroll
        for (int m = 0; m < 4; m++)
            af[m] = *(const short8*)(hT + loff(m * 16 + l15, ks * 64 + lhi * 16));
        #pragma unroll
        for (int m = 0; m < 4; m++)
            #pragma unroll
            for (int nf = 0; nf < 2; nf++)
                acc[m][nf] = __builtin_amdgcn_mfma_f32_16x16x32_bf16(af[m], bf[ks][nf], acc[m][nf], 0, 0, 0);
    }
    __syncthreads();   // drain phase-A reads before overwrite

    #pragma unroll
    for (int m = 0; m < 4; m++)
        #pragma unroll
        for (int nf = 0; nf < 2; nf++) {
            int colb = (ncol0 + nf * 16 + l15) * 2;
            #pragma unroll
            for (int j = 0; j < 4; j++) {
                int row = m * 16 + lhi * 4 + j;
                float t = acc[m][nf][j];
                t = t > 0.f ? t : 0.f;
                *(ushort*)(hT + loff(row, colb)) = (ushort)bfround(t);
            }
        }
    __syncthreads();

    #pragma unroll
    for (int ks = 0; ks < 4; ks++)
        #pragma unroll
        for (int nf = 0; nf < 2; nf++) {
            int nrow = ncol0 + nf * 16 + l15;
            bf[ks][nf] = *(const short8*)(W2t + nrow * 128 + ks * 32 + lhi * 8);
        }
    #pragma unroll
    for (int m = 0; m < 4; m++)
        #pragma unroll
        for (int nf = 0; nf < 2; nf++) {
            float bias = b2[ncol0 + nf * 16 + l15];
            acc[m][nf] = (floatx4){bias, bias, bias, bias};
        }

    #pragma unroll
    for (int ks = 0; ks < 4; ks++) {
        short8 af[4];
        #pragma unroll
        for (int m = 0; m < 4; m++)
            af[m] = *(const short8*)(hT + loff(m * 16 + l15, ks * 64 + lhi * 16));
        #pragma unroll
        for (int m = 0; m < 4; m++)
            #pragma unroll
            for (int nf = 0; nf < 2; nf++)
                acc[m][nf] = __builtin_amdgcn_mfma_f32_16x16x32_bf16(af[m], bf[ks][nf], acc[m][nf], 0, 0, 0);
    }
    __syncthreads();   // drain phase-B reads before overwrite

    #pragma unroll
    for (int m = 0; m < 4; m++)
        #pragma unroll
        for (int nf = 0; nf < 2; nf++) {
            int colb = (ncol0 + nf * 16 + l15) * 2;
            #pragma unroll
            for (int j = 0; j < 4; j++) {
                int row = m * 16 + lhi * 4 + j;
                float t = acc[m][nf][j];
                t = t > 0.f ? t : 0.f;
                *(ushort*)(hT + loff(row, colb)) = (ushort)bfround(t);
            }
        }
    __syncthreads();
    #pragma unroll
    for (int it = 0; it < 4; ++it) {
        int idx = it * 256 + tid;
        int row = idx >> 4;
        int cb = (idx & 15) * 16;
        int gn = node0 + row;
        if (gn < N_NODES)
            *(floatx4*)(xout + (size_t)gn * 128 + cb / 2) = *(const floatx4*)(hT + loff(row, cb));
    }
}

// ---------------- global add pool (node-parallel, batch sorted) ----------------
__global__ __launch_bounds__(256) void k_pool(const uint* __restrict__ x,
                                              const int* __restrict__ batch,
                                              float* __restrict__ pooled) {
    int n0 = blockIdx.x * POOL_CHUNK;
    int wave = threadIdx.x >> 6;
    int lane = threadIdx.x & 63;
    float a0 = 0.f, a1 = 0.f;
    int cur = -1;
    int endn = min(n0 + POOL_CHUNK, N_NODES);
    for (int n = n0 + wave; n < endn; n += 4) {
        int g = batch[n];                      // wave-uniform
        if (g != cur) {
            if (cur >= 0) {
                atomicAdd(&pooled[cur * 128 + lane * 2], a0);
                atomicAdd(&pooled[cur * 128 + lane * 2 + 1], a1);
            }
            cur = g; a0 = 0.f; a1 = 0.f;
        }
        uint v = x[(size_t)n * 64 + lane];     // 256B/row coalesced
        a0 += bflo(v); a1 += bfhi(v);
    }
    if (cur >= 0) {
        atomicAdd(&pooled[cur * 128 + lane * 2], a0);
        atomicAdd(&pooled[cur * 128 + lane * 2 + 1], a1);
    }
}

__global__ __launch_bounds__(64) void k_final(const float* __restrict__ pooled,
                                              const float* __restrict__ wl,
                                              const float* __restrict__ bl,
                                              float* __restrict__ out) {
    int g = blockIdx.x;
    int o = threadIdx.x;
    if (o >= N_CLASSES) return;
    float acc = bl[o];
    for (int k = 0; k < 128; k++) acc += pooled[g * 128 + k] * wl[k * N_CLASSES + o];
    out[g * N_CLASSES + o] = acc;
}

// ---------------- launch ----------------

extern "C" void kernel_launch(void* const* d_in, const int* in_sizes, int n_in,
                              void* d_out, int out_size, void* d_ws, size_t ws_size,
                              hipStream_t stream) {
    const float* x0  = (const float*)d_in[0];
    const int* ei    = (const int*)d_in[1];
    const int* batch = (const int*)d_in[2];
    const float* W1[3] = {(const float*)d_in[3], (const float*)d_in[7],  (const float*)d_in[11]};
    const float* B1[3] = {(const float*)d_in[4], (const float*)d_in[8],  (const float*)d_in[12]};
    const float* W2[3] = {(const float*)d_in[5], (const float*)d_in[9],  (const float*)d_in[13]};
    const float* B2[3] = {(const float*)d_in[6], (const float*)d_in[10], (const float*)d_in[14]};
    const float* wl = (const float*)d_in[15];
    const float* bl = (const float*)d_in[16];
    float* out = (float*)d_out;

    const int* srcv = ei;
    const int* dstv = ei + N_EDGES;

    // workspace layout
    char* w = (char*)d_ws;
    ushort* xb = (ushort*)w;                                   // N*128 bf16 (25.6MB)
    ushort* hb = xb + (size_t)N_NODES * DIM;                   // N*128 bf16 (25.6MB)
    ushort* wt = hb + (size_t)N_NODES * DIM;                   // 6*128*128 bf16
    float* pooled = (float*)(wt + 6 * 128 * 128);              // 512*128 f32
    int* row_ptr = (int*)(pooled + N_GRAPHS * DIM);            // N+2
    int* colidx  = row_ptr + (N_NODES + 2);                    // E (6.4MB)
    int* chunk_sums = colidx + N_EDGES;                        // 256
    int* hist    = chunk_sums + 256;                           // HN+1 (613KB)
    uint* sorted = (uint*)(hist + HN + 1);                     // E (6.4MB)

    // ---- conversion (x + weights) ----
    WPtrs wp;
    wp.w[0] = W1[0]; wp.w[1] = W2[0]; wp.w[2] = W1[1];
    wp.w[3] = W2[1]; wp.w[4] = W1[2]; wp.w[5] = W2[2];
    hipLaunchKernelGGL(k_cvt_x, dim3(2048), dim3(256), 0, stream, x0, xb, wp, wt);

    // ---- CSR build: 2-pass radix (hist also zero-inits pooled) ----
    hipLaunchKernelGGL(k_hist, dim3(NEB), dim3(256), 0, stream, dstv, hist, pooled);
    hipLaunchKernelGGL(k_reduce, dim3(NCH_HIST), dim3(256), 0, stream, hist, HN, chunk_sums);
    hipLaunchKernelGGL(k_scan_c, dim3(1), dim3(256), 0, stream, chunk_sums, NCH_HIST);
    hipLaunchKernelGGL(k_apply, dim3(NCH_HIST), dim3(256), 0, stream, hist, chunk_sums, hist, HN);
    hipLaunchKernelGGL(k_scatter, dim3(NEB), dim3(256), 0, stream, srcv, dstv, hist, sorted);
    hipLaunchKernelGGL(k_build, dim3(NBK), dim3(256), 0, stream, hist, sorted, row_ptr, colidx);

    // ---- 3 GIN layers: agg (xb -> hb), mlp (hb -> xb) ----
    dim3 aggGrid((N_NODES + 7) / 8), aggBlk(256);   // 2 nodes/wave, 8/block
    dim3 mlpGrid((N_NODES + 63) / 64), mlpBlk(256);
    for (int l = 0; l < 3; l++) {
        hipLaunchKernelGGL(k_agg, aggGrid, aggBlk, 0, stream,
                           (const uint4*)xb, row_ptr, colidx, (uint4*)hb);
        hipLaunchKernelGGL(k_mlp, mlpGrid, mlpBlk, 0, stream,
                           hb, xb, wt + (size_t)(2 * l) * 16384, B1[l],
                           wt + (size_t)(2 * l + 1) * 16384, B2[l]);
    }

    // ---- pool + final ----
    hipLaunchKernelGGL(k_pool, dim3(NPB), dim3(256), 0, stream, (const uint*)xb, batch, pooled);
    hipLaunchKernelGGL(k_final, dim3(N_GRAPHS), dim3(64), 0, stream, pooled, wl, bl, out);
}

// Round 14
// 314.225 us; speedup vs baseline: 1.0975x; 1.0523x over previous
//
#include <hip/hip_runtime.h>
#include <hip/hip_bf16.h>

#define N_NODES 100000
#define N_EDGES 1600000
#define DIM 128
#define N_GRAPHS 512
#define N_CLASSES 10
#define SCAN_CHUNK 1024

// 2-pass radix CSR build
#define NBK 782                 // buckets of 128 dst nodes
#define EB 8192                 // edges per histogram/scatter block
#define NEB 196                 // ceil(N_EDGES / EB)
#define HN (NBK * NEB)          // 153272 hist entries (bucket-major)
#define NCH_HIST ((HN + SCAN_CHUNK - 1) / SCAN_CHUNK)       // 150

typedef __attribute__((ext_vector_type(8))) short short8;
typedef __attribute__((ext_vector_type(4))) float floatx4;

__device__ __forceinline__ uint bfround(float f) {   // fp32 -> bf16 bits (RNE)
    uint u = __builtin_bit_cast(uint, f);
    return (u + 0x7fffu + ((u >> 16) & 1u)) >> 16;
}
__device__ __forceinline__ float bflo(uint u) { return __builtin_bit_cast(float, u << 16); }
__device__ __forceinline__ float bfhi(uint u) { return __builtin_bit_cast(float, u & 0xffff0000u); }

__device__ __forceinline__ void addrow(float* a, uint4 v) {
    a[0] += bflo(v.x); a[1] += bfhi(v.x);
    a[2] += bflo(v.y); a[3] += bfhi(v.y);
    a[4] += bflo(v.z); a[5] += bfhi(v.z);
    a[6] += bflo(v.w); a[7] += bfhi(v.w);
}

struct WPtrs { const float* w[6]; };

// ---------------- merged: dtype conversion (x + weights) AND edge histogram ----
// blocks [0, NEB): per-edge-block LDS histogram -> hist[b*NEB+blk], + pooled zero
// blocks [NEB, ...): grid-stride bf16 conversion of x and the 6 weight matrices
__global__ __launch_bounds__(256) void k_cvt_hist(const float* __restrict__ x,
                                                  ushort* __restrict__ xb,
                                                  WPtrs wp, ushort* __restrict__ wt,
                                                  const int* __restrict__ dstv,
                                                  int* __restrict__ hist,
                                                  float* __restrict__ pooled) {
    __shared__ int cnt[NBK];
    int tid = threadIdx.x;
    if (blockIdx.x < NEB) {
        int blk = blockIdx.x;
        int gt = blk * 256 + tid;
        for (int i = gt; i < N_GRAPHS * DIM; i += NEB * 256) pooled[i] = 0.f;
        for (int i = tid; i < NBK; i += 256) cnt[i] = 0;
        __syncthreads();
        int base = blk * EB;
        int end = min(base + EB, N_EDGES);
        for (int i = base + tid; i < end; i += 256) atomicAdd(&cnt[dstv[i] >> 7], 1);
        __syncthreads();
        for (int b = tid; b < NBK; b += 256) hist[b * NEB + blk] = cnt[b];
    } else {
        int stride = (gridDim.x - NEB) * 256;
        int t0 = (blockIdx.x - NEB) * 256 + tid;
        for (int i = t0; i < N_NODES * DIM / 4; i += stride) {
            floatx4 v = *(const floatx4*)(x + (size_t)i * 4);
            ushort4 o;
            o.x = (ushort)bfround(v.x);
            o.y = (ushort)bfround(v.y);
            o.z = (ushort)bfround(v.z);
            o.w = (ushort)bfround(v.w);
            *(ushort4*)(xb + (size_t)i * 4) = o;
        }
        for (int j = t0; j < 6 * 16384; j += stride) {
            int m = j >> 14, idx = j & 16383;
            int n = idx >> 7, k = idx & 127;
            wt[j] = (ushort)bfround(wp.w[m][k * 128 + n]);
        }
    }
}

// ---- hierarchical exclusive scan over hist: reduce, then apply (scan inlined) ----
__global__ __launch_bounds__(256) void k_reduce(const int* __restrict__ src, int n,
                                                int* __restrict__ chunk_sums) {
    int base = blockIdx.x * SCAN_CHUNK;
    int tid = threadIdx.x;
    int s = 0;
    for (int i = tid; i < SCAN_CHUNK; i += 256) {
        int idx = base + i;
        if (idx < n) s += src[idx];
    }
    __shared__ int red[256];
    red[tid] = s;
    __syncthreads();
    for (int off = 128; off > 0; off >>= 1) {
        if (tid < off) red[tid] += red[tid + off];
        __syncthreads();
    }
    if (tid == 0) chunk_sums[blockIdx.x] = red[0];
}

// exclusive scan apply with inline chunk-prefix (reads UNSCANNED chunk_sums);
// safe in-place (src==dst): each block touches only its own chunk
__global__ __launch_bounds__(256) void k_apply(const int* __restrict__ src,
                                               const int* __restrict__ chunk_sums,
                                               int nch,
                                               int* __restrict__ dst, int n) {
    int tid = threadIdx.x;
    // prefix = sum of chunk_sums[0..blockIdx.x)
    __shared__ int red[256];
    int ps = (tid < blockIdx.x && tid < nch) ? chunk_sums[tid] : 0;
    red[tid] = ps;
    __syncthreads();
    for (int off = 128; off > 0; off >>= 1) {
        if (tid < off) red[tid] += red[tid + off];
        __syncthreads();
    }
    int prefix = red[0];
    __syncthreads();

    int base = blockIdx.x * SCAN_CHUNK;
    int i0 = base + tid * 4;
    int v[4];
    int s = 0;
    #pragma unroll
    for (int j = 0; j < 4; j++) {
        int idx = i0 + j;
        v[j] = (idx < n) ? src[idx] : 0;
        s += v[j];
    }
    __shared__ int sc[256];
    sc[tid] = s;
    __syncthreads();
    for (int off = 1; off < 256; off <<= 1) {
        int t = (tid >= off) ? sc[tid - off] : 0;
        __syncthreads();
        sc[tid] += t;
        __syncthreads();
    }
    int excl = sc[tid] - s + prefix;
    #pragma unroll
    for (int j = 0; j < 4; j++) {
        int idx = i0 + j;
        if (idx < n) dst[idx] = excl;
        excl += v[j];
    }
}

// pass 2: scatter edges into bucket-sorted array. LDS cursor seeded with the
// global scanned base -> each (block,bucket) chunk is contiguous in memory.
// entry = src | (dst&127)<<17.
__global__ __launch_bounds__(256) void k_scatter(const int* __restrict__ srcv,
                                                 const int* __restrict__ dstv,
                                                 const int* __restrict__ hists,
                                                 uint* __restrict__ sorted) {
    __shared__ int cur[NBK];
    int blk = blockIdx.x, tid = threadIdx.x;
    for (int b = tid; b < NBK; b += 256) cur[b] = hists[b * NEB + blk];
    __syncthreads();
    int base = blk * EB;
    int end = min(base + EB, N_EDGES);
    for (int i = base + tid; i < end; i += 256) {
        int s = srcv[i], d = dstv[i];
        int p = atomicAdd(&cur[d >> 7], 1);
        sorted[p] = (uint)s | ((uint)(d & 127) << 17);
    }
}

// merged bcount + per-node scan + fill (replaces 5 kernels)
__global__ __launch_bounds__(256) void k_build(const int* __restrict__ hists,
                                               const uint* __restrict__ sorted,
                                               int* __restrict__ row_ptr,
                                               int* __restrict__ col) {
    __shared__ int cnt[128];
    __shared__ int scn[128];
    __shared__ int cur[128];
    int b = blockIdx.x, tid = threadIdx.x;
    if (tid < 128) cnt[tid] = 0;
    __syncthreads();
    int s0 = hists[b * NEB];
    int s1 = (b == NBK - 1) ? N_EDGES : hists[(b + 1) * NEB];
    for (int i = s0 + tid; i < s1; i += 256) atomicAdd(&cnt[(sorted[i] >> 17) & 127], 1);
    __syncthreads();
    if (tid < 128) scn[tid] = cnt[tid];
    __syncthreads();
    for (int off = 1; off < 128; off <<= 1) {
        int t = (tid < 128 && tid >= off) ? scn[tid - off] : 0;
        __syncthreads();
        if (tid < 128) scn[tid] += t;
        __syncthreads();
    }
    int node = (b << 7) + tid;
    if (tid < 128) {
        int excl = s0 + scn[tid] - cnt[tid];
        cur[tid] = excl;
        if (node < N_NODES) row_ptr[node] = excl;
    }
    if (b == 0 && tid == 0) row_ptr[N_NODES] = N_EDGES;
    __syncthreads();
    for (int i = s0 + tid; i < s1; i += 256) {
        uint e = sorted[i];
        int p = atomicAdd(&cur[(e >> 17) & 127], 1);
        col[p] = (int)(e & 0x1FFFFu);
    }
}

// ---------------- GIN aggregation: 2 nodes per wave, 8 loads in flight ------
// AT ROOFLINE (R8 vs R11 A/B: 4-deep and 8-deep both 60us, fetch 187MB @ 3.6TB/s
// -> random-256B-gather fabric bound). Uniform trips, clamped shfl (R3 lesson).
__global__ __launch_bounds__(256) void k_agg(const uint4* __restrict__ xr,
                                             const int* __restrict__ row_ptr,
                                             const int* __restrict__ col,
                                             uint4* __restrict__ hr) {
    int wv = threadIdx.x >> 6;
    int nA = blockIdx.x * 8 + wv * 2;      // wave-uniform
    if (nA >= N_NODES) return;
    int nB = nA + 1;
    bool hasB = nB < N_NODES;
    int lane = threadIdx.x & 63;
    int grp = lane >> 4;
    int l16 = lane & 15;

    float accA[8], accB[8];
    #pragma unroll
    for (int i = 0; i < 8; i++) { accA[i] = 0.f; accB[i] = 0.f; }
    if (grp == 0) {
        uint4 sv = xr[(size_t)nA * 16 + l16];      // self term A (eps=0)
        accA[0] = bflo(sv.x); accA[1] = bfhi(sv.x);
        accA[2] = bflo(sv.y); accA[3] = bfhi(sv.y);
        accA[4] = bflo(sv.z); accA[5] = bfhi(sv.z);
        accA[6] = bflo(sv.w); accA[7] = bfhi(sv.w);
    } else if (grp == 1 && hasB) {
        uint4 sv = xr[(size_t)nB * 16 + l16];      // self term B
        accB[0] = bflo(sv.x); accB[1] = bfhi(sv.x);
        accB[2] = bflo(sv.y); accB[3] = bfhi(sv.y);
        accB[4] = bflo(sv.z); accB[5] = bfhi(sv.z);
        accB[6] = bflo(sv.w); accB[7] = bfhi(sv.w);
    }

    int jA = row_ptr[nA], eA = row_ptr[nA + 1];
    int jB = hasB ? row_ptr[nB] : 0;
    int eB = hasB ? row_ptr[nB + 1] : 0;

    while (jA < eA || jB < eB) {
        int chunkA = eA - jA; chunkA = chunkA < 0 ? 0 : (chunkA > 64 ? 64 : chunkA);
        int chunkB = eB - jB; chunkB = chunkB < 0 ? 0 : (chunkB > 64 ? 64 : chunkB);
        int myA = (lane < chunkA) ? col[jA + lane] : 0;
        int myB = (lane < chunkB) ? col[jB + lane] : 0;
        int cm = chunkA > chunkB ? chunkA : chunkB;
        int iters = (cm + 15) >> 4;             // wave-uniform
        for (int f = 0; f < iters; f++) {
            int p = (f << 4) + grp;
            int a0 = __shfl(myA, (p      < chunkA) ? p      : 0);
            int a1 = __shfl(myA, (p + 4  < chunkA) ? p + 4  : 0);
            int a2 = __shfl(myA, (p + 8  < chunkA) ? p + 8  : 0);
            int a3 = __shfl(myA, (p + 12 < chunkA) ? p + 12 : 0);
            int b0 = __shfl(myB, (p      < chunkB) ? p      : 0);
            int b1 = __shfl(myB, (p + 4  < chunkB) ? p + 4  : 0);
            int b2 = __shfl(myB, (p + 8  < chunkB) ? p + 8  : 0);
            int b3 = __shfl(myB, (p + 12 < chunkB) ? p + 12 : 0);
            uint4 vA0 = xr[(size_t)a0 * 16 + l16];   // 8 loads in flight
            uint4 vA1 = xr[(size_t)a1 * 16 + l16];
            uint4 vA2 = xr[(size_t)a2 * 16 + l16];
            uint4 vA3 = xr[(size_t)a3 * 16 + l16];
            uint4 vB0 = xr[(size_t)b0 * 16 + l16];
            uint4 vB1 = xr[(size_t)b1 * 16 + l16];
            uint4 vB2 = xr[(size_t)b2 * 16 + l16];
            uint4 vB3 = xr[(size_t)b3 * 16 + l16];
            if (p < chunkA)      addrow(accA, vA0);
            if (p + 4 < chunkA)  addrow(accA, vA1);
            if (p + 8 < chunkA)  addrow(accA, vA2);
            if (p + 12 < chunkA) addrow(accA, vA3);
            if (p < chunkB)      addrow(accB, vB0);
            if (p + 4 < chunkB)  addrow(accB, vB1);
            if (p + 8 < chunkB)  addrow(accB, vB2);
            if (p + 12 < chunkB) addrow(accB, vB3);
        }
        jA += 64; jB += 64;
    }

    #pragma unroll
    for (int i = 0; i < 8; i++) {
        accA[i] += __shfl_xor(accA[i], 16);
        accA[i] += __shfl_xor(accA[i], 32);
        accB[i] += __shfl_xor(accB[i], 16);
        accB[i] += __shfl_xor(accB[i], 32);
    }

    if (grp == 0) {
        uint4 o;
        o.x = bfround(accA[0]) | (bfround(accA[1]) << 16);
        o.y = bfround(accA[2]) | (bfround(accA[3]) << 16);
        o.z = bfround(accA[4]) | (bfround(accA[5]) << 16);
        o.w = bfround(accA[6]) | (bfround(accA[7]) << 16);
        hr[(size_t)nA * 16 + l16] = o;
    } else if (grp == 1 && hasB) {
        uint4 o;
        o.x = bfround(accB[0]) | (bfround(accB[1]) << 16);
        o.y = bfround(accB[2]) | (bfround(accB[3]) << 16);
        o.z = bfround(accB[4]) | (bfround(accB[5]) << 16);
        o.w = bfround(accB[6]) | (bfround(accB[7]) << 16);
        hr[(size_t)nB * 16 + l16] = o;
    }
}

// ---------------- fused MFMA MLP (staged, single 16KB LDS buffer) -----------
// dopool!=0 (last layer): after staging the output tile, each wave also
// accumulates its 16 rows into pooled[] straight from LDS (k_pool fused; the
// 16B-granular XOR swizzle preserves 4B substructure, so the uint at
// loff(row, lane*4) is exactly channels {2*lane, 2*lane+1}).
__device__ __forceinline__ int loff(int row, int byte) {
    return row * 256 + (byte ^ ((row & 7) << 4));
}

__global__ __launch_bounds__(256) void k_mlp(const ushort* __restrict__ hin,
                                             ushort* __restrict__ xout,
                                             const ushort* __restrict__ W1t,
                                             const float* __restrict__ b1,
                                             const ushort* __restrict__ W2t,
                                             const float* __restrict__ b2,
                                             const int* __restrict__ batch,
                                             float* __restrict__ pooled,
                                             int dopool) {
    __shared__ alignas(16) char hT[64 * 256];   // h, then t, then out
    int tid = threadIdx.x;
    int lane = tid & 63;
    int wave = tid >> 6;
    int node0 = blockIdx.x * 64;
    int l15 = lane & 15;
    int lhi = lane >> 4;
    int ncol0 = wave * 32;

    #pragma unroll
    for (int it = 0; it < 4; ++it) {
        int idx = it * 256 + tid;
        int row = idx >> 4;
        int cb = (idx & 15) * 16;
        int gn = node0 + row;
        floatx4 v = {0.f, 0.f, 0.f, 0.f};
        if (gn < N_NODES) v = *(const floatx4*)(hin + (size_t)gn * 128 + cb / 2);
        *(floatx4*)(hT + loff(row, cb)) = v;
    }
    __syncthreads();

    short8 bf[4][2];
    #pragma unroll
    for (int ks = 0; ks < 4; ks++)
        #pragma unroll
        for (int nf = 0; nf < 2; nf++) {
            int nrow = ncol0 + nf * 16 + l15;
            bf[ks][nf] = *(const short8*)(W1t + nrow * 128 + ks * 32 + lhi * 8);
        }

    floatx4 acc[4][2];
    #pragma unroll
    for (int m = 0; m < 4; m++)
        #pragma unroll
        for (int nf = 0; nf < 2; nf++) {
            float bias = b1[ncol0 + nf * 16 + l15];
            acc[m][nf] = (floatx4){bias, bias, bias, bias};
        }

    #pragma unroll
    for (int ks = 0; ks < 4; ks++) {
        short8 af[4];
        #pragma unroll
        for (int m = 0; m < 4; m++)
            af[m] = *(const short8*)(hT + loff(m * 16 + l15, ks * 64 + lhi * 16));
        #pragma unroll
        for (int m = 0; m < 4; m++)
            #pragma unroll
            for (int nf = 0; nf < 2; nf++)
                acc[m][nf] = __builtin_amdgcn_mfma_f32_16x16x32_bf16(af[m], bf[ks][nf], acc[m][nf], 0, 0, 0);
    }
    __syncthreads();   // drain phase-A reads before overwrite

    #pragma unroll
    for (int m = 0; m < 4; m++)
        #pragma unroll
        for (int nf = 0; nf < 2; nf++) {
            int colb = (ncol0 + nf * 16 + l15) * 2;
            #pragma unroll
            for (int j = 0; j < 4; j++) {
                int row = m * 16 + lhi * 4 + j;
                float t = acc[m][nf][j];
                t = t > 0.f ? t : 0.f;
                *(ushort*)(hT + loff(row, colb)) = (ushort)bfround(t);
            }
        }
    __syncthreads();

    #pragma unroll
    for (int ks = 0; ks < 4; ks++)
        #pragma unroll
        for (int nf = 0; nf < 2; nf++) {
            int nrow = ncol0 + nf * 16 + l15;
            bf[ks][nf] = *(const short8*)(W2t + nrow * 128 + ks * 32 + lhi * 8);
        }
    #pragma unroll
    for (int m = 0; m < 4; m++)
        #pragma unroll
        for (int nf = 0; nf < 2; nf++) {
            float bias = b2[ncol0 + nf * 16 + l15];
            acc[m][nf] = (floatx4){bias, bias, bias, bias};
        }

    #pragma unroll
    for (int ks = 0; ks < 4; ks++) {
        short8 af[4];
        #pragma unroll
        for (int m = 0; m < 4; m++)
            af[m] = *(const short8*)(hT + loff(m * 16 + l15, ks * 64 + lhi * 16));
        #pragma unroll
        for (int m = 0; m < 4; m++)
            #pragma unroll
            for (int nf = 0; nf < 2; nf++)
                acc[m][nf] = __builtin_amdgcn_mfma_f32_16x16x32_bf16(af[m], bf[ks][nf], acc[m][nf], 0, 0, 0);
    }
    __syncthreads();   // drain phase-B reads before overwrite

    #pragma unroll
    for (int m = 0; m < 4; m++)
        #pragma unroll
        for (int nf = 0; nf < 2; nf++) {
            int colb = (ncol0 + nf * 16 + l15) * 2;
            #pragma unroll
            for (int j = 0; j < 4; j++) {
                int row = m * 16 + lhi * 4 + j;
                float t = acc[m][nf][j];
                t = t > 0.f ? t : 0.f;
                *(ushort*)(hT + loff(row, colb)) = (ushort)bfround(t);
            }
        }
    __syncthreads();
    #pragma unroll
    for (int it = 0; it < 4; ++it) {
        int idx = it * 256 + tid;
        int row = idx >> 4;
        int cb = (idx & 15) * 16;
        int gn = node0 + row;
        if (gn < N_NODES)
            *(floatx4*)(xout + (size_t)gn * 128 + cb / 2) = *(const floatx4*)(hT + loff(row, cb));
    }

    // ---- fused global-add-pool (last layer only); batch is sorted ----
    if (dopool) {
        float a0 = 0.f, a1 = 0.f;
        int cur = -1;
        for (int i = 0; i < 16; i++) {
            int row = wave * 16 + i;
            int gn = node0 + row;
            if (gn >= N_NODES) break;          // wave-uniform
            int g = batch[gn];                 // wave-uniform
            if (g != cur) {
                if (cur >= 0) {
                    atomicAdd(&pooled[cur * 128 + lane * 2], a0);
                    atomicAdd(&pooled[cur * 128 + lane * 2 + 1], a1);
                }
                cur = g; a0 = 0.f; a1 = 0.f;
            }
            uint v = *(const uint*)(hT + loff(row, lane * 4));
            a0 += bflo(v); a1 += bfhi(v);
        }
        if (cur >= 0) {
            atomicAdd(&pooled[cur * 128 + lane * 2], a0);
            atomicAdd(&pooled[cur * 128 + lane * 2 + 1], a1);
        }
    }
}

__global__ __launch_bounds__(64) void k_final(const float* __restrict__ pooled,
                                              const float* __restrict__ wl,
                                              const float* __restrict__ bl,
                                              float* __restrict__ out) {
    int g = blockIdx.x;
    int o = threadIdx.x;
    if (o >= N_CLASSES) return;
    float acc = bl[o];
    for (int k = 0; k < 128; k++) acc += pooled[g * 128 + k] * wl[k * N_CLASSES + o];
    out[g * N_CLASSES + o] = acc;
}

// ---------------- launch ----------------

extern "C" void kernel_launch(void* const* d_in, const int* in_sizes, int n_in,
                              void* d_out, int out_size, void* d_ws, size_t ws_size,
                              hipStream_t stream) {
    const float* x0  = (const float*)d_in[0];
    const int* ei    = (const int*)d_in[1];
    const int* batch = (const int*)d_in[2];
    const float* W1[3] = {(const float*)d_in[3], (const float*)d_in[7],  (const float*)d_in[11]};
    const float* B1[3] = {(const float*)d_in[4], (const float*)d_in[8],  (const float*)d_in[12]};
    const float* W2[3] = {(const float*)d_in[5], (const float*)d_in[9],  (const float*)d_in[13]};
    const float* B2[3] = {(const float*)d_in[6], (const float*)d_in[10], (const float*)d_in[14]};
    const float* wl = (const float*)d_in[15];
    const float* bl = (const float*)d_in[16];
    float* out = (float*)d_out;

    const int* srcv = ei;
    const int* dstv = ei + N_EDGES;

    // workspace layout
    char* w = (char*)d_ws;
    ushort* xb = (ushort*)w;                                   // N*128 bf16 (25.6MB)
    ushort* hb = xb + (size_t)N_NODES * DIM;                   // N*128 bf16 (25.6MB)
    ushort* wt = hb + (size_t)N_NODES * DIM;                   // 6*128*128 bf16
    float* pooled = (float*)(wt + 6 * 128 * 128);              // 512*128 f32
    int* row_ptr = (int*)(pooled + N_GRAPHS * DIM);            // N+2
    int* colidx  = row_ptr + (N_NODES + 2);                    // E (6.4MB)
    int* chunk_sums = colidx + N_EDGES;                        // 256
    int* hist    = chunk_sums + 256;                           // HN+1 (613KB)
    uint* sorted = (uint*)(hist + HN + 1);                     // E (6.4MB)

    // ---- merged conversion + histogram (+ pooled zero-init) ----
    WPtrs wp;
    wp.w[0] = W1[0]; wp.w[1] = W2[0]; wp.w[2] = W1[1];
    wp.w[3] = W2[1]; wp.w[4] = W1[2]; wp.w[5] = W2[2];
    hipLaunchKernelGGL(k_cvt_hist, dim3(2048 + NEB), dim3(256), 0, stream,
                       x0, xb, wp, wt, dstv, hist, pooled);

    // ---- CSR build: 2-pass radix ----
    hipLaunchKernelGGL(k_reduce, dim3(NCH_HIST), dim3(256), 0, stream, hist, HN, chunk_sums);
    hipLaunchKernelGGL(k_apply, dim3(NCH_HIST), dim3(256), 0, stream,
                       hist, chunk_sums, NCH_HIST, hist, HN);
    hipLaunchKernelGGL(k_scatter, dim3(NEB), dim3(256), 0, stream, srcv, dstv, hist, sorted);
    hipLaunchKernelGGL(k_build, dim3(NBK), dim3(256), 0, stream, hist, sorted, row_ptr, colidx);

    // ---- 3 GIN layers: agg (xb -> hb), mlp (hb -> xb); pool fused into l=2 ----
    dim3 aggGrid((N_NODES + 7) / 8), aggBlk(256);   // 2 nodes/wave, 8/block
    dim3 mlpGrid((N_NODES + 63) / 64), mlpBlk(256);
    for (int l = 0; l < 3; l++) {
        hipLaunchKernelGGL(k_agg, aggGrid, aggBlk, 0, stream,
                           (const uint4*)xb, row_ptr, colidx, (uint4*)hb);
        hipLaunchKernelGGL(k_mlp, mlpGrid, mlpBlk, 0, stream,
                           hb, xb, wt + (size_t)(2 * l) * 16384, B1[l],
                           wt + (size_t)(2 * l + 1) * 16384, B2[l],
                           batch, pooled, (l == 2) ? 1 : 0);
    }

    // ---- final linear ----
    hipLaunchKernelGGL(k_final, dim3(N_GRAPHS), dim3(64), 0, stream, pooled, wl, bl, out);
}